// Round 17
// baseline (3821.730 us; speedup 1.0000x reference)
//
#include <hip/hip_runtime.h>
#include <hip/hip_bf16.h>

#define T 4096
#define BT (16*4096)
#define NL 20
#define TPB 4608   // 512 pad + 4096 tokens per batch
#define PAD 512

typedef __bf16 bf16;
typedef __bf16 v8bf __attribute__((ext_vector_type(8)));
typedef float v4f __attribute__((ext_vector_type(4)));
typedef unsigned int uint32;
typedef unsigned short ushort16;

#define MFMA(a,b,c) __builtin_amdgcn_mfma_f32_16x16x32_bf16((a),(b),(c),0,0,0)

__device__ __forceinline__ int swz512(int row, int bc)  { return row*512  + (bc ^ ((row&7)<<4)); }

__device__ __forceinline__ void gload16(const void* g, void* l) {
    __builtin_amdgcn_global_load_lds(
        (const __attribute__((address_space(1))) void*)g,
        (__attribute__((address_space(3))) void*)l, 16, 0, 0);
}

__device__ __forceinline__ ushort16 bfbits(float v) {
    bf16 h = (bf16)v; return *(ushort16*)&h;
}
__device__ __forceinline__ float u16f(uint32 lo16) { uint32 t = lo16 << 16; return *(float*)&t; }
__device__ __forceinline__ float sel_f(uint32 pair, int j) {  // j&1: 0=lo,1=hi
    uint32 t = (j & 1) ? (pair & 0xffff0000u) : (pair << 16);
    return *(float*)&t;
}
__device__ __forceinline__ uint32 scale_pair(uint32 v, float s) {
    uint32 lo = v << 16, hi = v & 0xffff0000u;
    float flo = *(float*)&lo * s, fhi = *(float*)&hi * s;
    return (uint32)bfbits(flo) | ((uint32)bfbits(fhi) << 16);
}
__device__ __forceinline__ float sq_pair(uint32 v) {
    uint32 lo = v << 16, hi = v & 0xffff0000u;
    float flo = *(float*)&lo, fhi = *(float*)&hi;
    return flo*flo + fhi*fhi;
}
__device__ __forceinline__ float tanh_clamped(float fv) {
    fv = fminf(fmaxf(fv, -20.f), 20.f);
    float e2 = __expf(-2.f * fv);
    return (1.f - e2) / (1.f + e2);
}
__device__ __forceinline__ float sigmoidf_(float v) {
    return 1.f / (1.f + __expf(-v));
}

// ---------------- zero pad stripes of zn ping-pong and iv ping-pong buffers ----------------
__global__ void zero_pads(bf16* __restrict__ za, bf16* __restrict__ zb,
                          float* __restrict__ iva, float* __restrict__ ivb) {
    int idx = blockIdx.x * 256 + threadIdx.x;      // 524288 + 4096 uint4
    if (idx < 524288) {
        int buf = idx >> 18;
        int r = idx & 262143;
        int b = r >> 14, off = r & 16383;          // pad = 512 rows * 32 uint4
        bf16* base = buf ? zb : za;
        ((uint4*)(base + (size_t)b * TPB * 256))[off] = make_uint4(0, 0, 0, 0);
    } else {
        int j = idx - 524288;                      // 2 bufs * 16 batches * 128 uint4
        int buf = j >> 11;
        int r = j & 2047;
        int b = r >> 7, off = r & 127;
        float* base = buf ? ivb : iva;
        ((uint4*)(base + (size_t)b * TPB))[off] = make_uint4(0, 0, 0, 0);
    }
}

// ---------------- prep kernels: cast/reorder weights to bf16 (norm_w folded into K) ----------
__global__ void prep_w2(const float* __restrict__ Wf, const float* __restrict__ Wg,
                        const float* __restrict__ norm_w,
                        bf16* __restrict__ wf0, bf16* __restrict__ wf1,
                        bf16* __restrict__ wg0, bf16* __restrict__ wg1) {
    int idx = blockIdx.x * 256 + threadIdx.x;       // NL*256*256, (layer, n, k)
    float nwv = norm_w[(idx >> 16) * 256 + (idx & 255)];
    const float* pf = Wf + (size_t)idx * 2;
    wf0[idx] = (bf16)(pf[0] * nwv); wf1[idx] = (bf16)(pf[1] * nwv);
    const float* pg = Wg + (size_t)idx * 2;
    wg0[idx] = (bf16)(pg[0] * nwv); wg1[idx] = (bf16)(pg[1] * nwv);
}

__global__ void prep_w1(const float* __restrict__ Wr, const float* __restrict__ Ws,
                        bf16* __restrict__ wr, bf16* __restrict__ ws) {
    int idx = blockIdx.x * 256 + threadIdx.x;       // NL*256*256 (A=U, no norm fold)
    wr[idx] = (bf16)Wr[idx]; ws[idx] = (bf16)Ws[idx];
}

__global__ void prep_misc(const float* __restrict__ W_in, const float* __restrict__ W1,
                          const float* __restrict__ W2, const float* __restrict__ hnw,
                          bf16* __restrict__ winb, bf16* __restrict__ w1b, bf16* __restrict__ w2b) {
    int idx = blockIdx.x * 256 + threadIdx.x;       // 458752 total
    if (idx < 65536) {
        int c = idx >> 8, jj = idx & 255, k = jj >> 3, ci = jj & 7;
        winb[idx] = (bf16)W_in[c * 256 + ci * 32 + k];   // winb[c][k*8+ci]
    } else if (idx < 327680) {
        int j = idx - 65536;                             // (h, k): fold head norm weight
        w1b[j] = (bf16)(W1[j] * hnw[j & 255]);
    } else {
        int j = idx - 327680; w2b[j] = (bf16)W2[j];
    }
}

// ---------------- fused input conv: x windows -> zn (normalized bf16) + iv ----------------
__global__ __launch_bounds__(512, 4) void in_conv_kernel(
    const float* __restrict__ x, const bf16* __restrict__ winb,
    const float* __restrict__ b_in,
    bf16* __restrict__ znout, float* __restrict__ ivout) {
    __shared__ __align__(16) char smem[65536];
    char* cW  = smem + 32768;                 // window tile
    char* cZn = smem;                         // z staging
    const int tid = threadIdx.x;
    const int g0 = blockIdx.x * 64;
    const int tl0 = g0 & (T - 1);
    const size_t pr0 = (size_t)(g0 >> 12) * TPB + PAD + tl0;
    for (int i = 0; i < 4; ++i) {
        int ch = tid + i * 512;
        int r = ch >> 5, c16 = ch & 31;
        int tok = tl0 + r - 31 + c16;
        bf16 t8[8] = {};
        if (tok >= 0) {
            const float* xr = x + (size_t)(g0 + r - 31 + c16) * 8;
            float4 xa = ((const float4*)xr)[0];
            float4 xb4 = ((const float4*)xr)[1];
            t8[0]=(bf16)xa.x; t8[1]=(bf16)xa.y; t8[2]=(bf16)xa.z; t8[3]=(bf16)xa.w;
            t8[4]=(bf16)xb4.x; t8[5]=(bf16)xb4.y; t8[6]=(bf16)xb4.z; t8[7]=(bf16)xb4.w;
        }
        *(uint4*)(cW + swz512(r, c16 * 16)) = *(uint4*)t8;
    }
    __syncthreads();
    const int lane = tid & 63, w = tid >> 6;
    const int l15 = lane & 15, l4 = lane >> 4;
    const int cbase = w * 32 + l15;

    uint32 zpk[2][4][2] = {};
    #pragma unroll
    for (int half = 0; half < 2; ++half) {
        v4f acc[4] = {};
        __builtin_amdgcn_s_setprio(1);
        #pragma unroll
        for (int ks = 0; ks < 8; ++ks) {
            v8bf b = *(const v8bf*)(winb + (size_t)(cbase + half*16)*256 + ks*32 + l4*8);
            #pragma unroll
            for (int m = 0; m < 4; ++m) {
                v8bf a = *(const v8bf*)(cW + swz512(m*16 + l15, ks*64 + l4*16));
                acc[m] = MFMA(a, b, acc[m]);
            }
        }
        __builtin_amdgcn_s_setprio(0);
        float bv = b_in[cbase + half*16];
        #pragma unroll
        for (int m = 0; m < 4; ++m)
            #pragma unroll
            for (int j = 0; j < 4; ++j) {
                float zf = acc[m][j] + bv;
                zpk[half][m][j>>1] |= (uint32)bfbits(zf) << ((j&1)*16);
            }
    }
    __syncthreads();                                  // window reads done
    #pragma unroll
    for (int m = 0; m < 4; ++m)
        #pragma unroll
        for (int j = 0; j < 4; ++j) {
            int row = m*16 + l4*4 + j;
            #pragma unroll
            for (int half = 0; half < 2; ++half) {
                int col = cbase + half*16;
                *(bf16*)(cZn + swz512(row, col*2)) = (bf16)sel_f(zpk[half][m][j>>1], j);
            }
        }
    __syncthreads();                                  // z tile complete
    // copyout + fused rsq + normalize-at-copyout (32 lanes per row hold the full row)
    #pragma unroll
    for (int k = 0; k < 4; ++k) {
        int idx = tid + k * 512;
        int row = idx >> 5, d = idx & 31;
        uint4 v = *(uint4*)(cZn + swz512(row, d*16));
        float p = sq_pair(v.x) + sq_pair(v.y) + sq_pair(v.z) + sq_pair(v.w);
        p += __shfl_xor(p,1); p += __shfl_xor(p,2); p += __shfl_xor(p,4);
        p += __shfl_xor(p,8); p += __shfl_xor(p,16);
        float iv = rsqrtf(p*(1.f/256.f) + 1e-6f);
        v.x = scale_pair(v.x, iv); v.y = scale_pair(v.y, iv);
        v.z = scale_pair(v.z, iv); v.w = scale_pair(v.w, iv);
        *((uint4*)(znout + (pr0 + row) * 256) + d) = v;
        if ((lane & 31) == 0) ivout[pr0 + row] = iv;
    }
}

// ---------------- fused gated-residual layer (256 threads, 32-token tiles) ----------------
// 4 waves; wave w owns cols [w*64, w*64+64) processed as 4 quarters of 16.
// zn exchanged normalized + iv; z_new normalized at copyout. mode: 0=first,1=mid,2=last
__global__ __launch_bounds__(256, 4) void layer_kernel(
    const bf16* __restrict__ znin, const float* __restrict__ ivin,
    bf16* __restrict__ znout, float* __restrict__ ivout, uint32* __restrict__ sumb,
    const bf16* __restrict__ wf0, const bf16* __restrict__ wf1,
    const bf16* __restrict__ wg0, const bf16* __restrict__ wg1,
    const bf16* __restrict__ wr, const bf16* __restrict__ wsm,
    const float* __restrict__ bfp, const float* __restrict__ bgp,
    const float* __restrict__ brp, const float* __restrict__ bsp,
    int dil, int mode) {
    __shared__ __align__(16) char smem[33024];
    char* cA0 = smem;                     // zn[t-d] (32 rows) -> U tile
    char* cA1 = smem + 16384;             // zn[t] -> z_new (in place)
    float* ivl = (float*)(smem + 32768);  // 32 floats: 1/iv[t]
    const int tid = threadIdx.x;
    const int lane = tid & 63, w = tid >> 6;        // w in 0..3
    const int g0 = blockIdx.x * 32;
    const size_t pr0 = (size_t)(g0 >> 12) * TPB + PAD + (g0 & (T - 1));

    const int rl = w * 8 + (lane >> 5);

    // async stage zn[t]->cA1, zn[t-dil]->cA0 with pre-swizzled global source
    {
        int d = lane & 31;
        #pragma unroll
        for (int j = 0; j < 4; ++j) {
            int r = rl + j * 2;
            int s = d ^ (r & 7);
            gload16(znin + (pr0 + r) * 256 + s * 8,       cA1 + (w*8 + j*2) * 512);
            gload16(znin + (pr0 + r - dil) * 256 + s * 8, cA0 + (w*8 + j*2) * 512);
        }
    }
    if (tid < 32) ivl[tid] = 1.f / ivin[pr0 + tid];   // riv for z_old reconstruction

    const int l15 = lane & 15, l4 = lane >> 4;
    uint32* zb_t = sumb + ((size_t)blockIdx.x * 256 + tid) * 16;

    __syncthreads();                               // S1: staging + ivl visible

    // ---- GEMM1: 4 col-quarters, fused taps ----
    uint32 upk[4][2][2] = {};                      // [q][m][jpair] packed bf16 u
    #pragma unroll
    for (int q = 0; q < 4; ++q) {
        const int qc = w*64 + q*16 + l15;
        v4f accf[2] = {}, accg[2] = {};
        __builtin_amdgcn_s_setprio(1);
        #pragma unroll
        for (int ks = 0; ks < 8; ++ks) {
            size_t bo = (size_t)qc * 256 + ks*32 + l4*8;
            v8bf bf0 = *(const v8bf*)(wf0 + bo);
            v8bf bf1 = *(const v8bf*)(wf1 + bo);
            v8bf bg0 = *(const v8bf*)(wg0 + bo);
            v8bf bg1 = *(const v8bf*)(wg1 + bo);
            #pragma unroll
            for (int m = 0; m < 2; ++m) {
                int off = swz512(m*16 + l15, ks*64 + l4*16);
                v8bf a0 = *(const v8bf*)(cA0 + off);
                v8bf a1 = *(const v8bf*)(cA1 + off);
                accf[m] = MFMA(a0, bf0, accf[m]);
                accf[m] = MFMA(a1, bf1, accf[m]);
                accg[m] = MFMA(a0, bg0, accg[m]);
                accg[m] = MFMA(a1, bg1, accg[m]);
            }
        }
        __builtin_amdgcn_s_setprio(0);
        float bfv = bfp[qc];
        float bgv = bgp[qc];
        #pragma unroll
        for (int m = 0; m < 2; ++m)
            #pragma unroll
            for (int j = 0; j < 4; ++j) {
                float u = tanh_clamped(accf[m][j] + bfv) * sigmoidf_(accg[m][j] + bgv);
                upk[q][m][j>>1] |= (uint32)bfbits(u) << ((j&1)*16);
            }
    }
    __syncthreads();                               // S2: all GEMM1 tile reads done (cA0 free)

    // write U tile (bf16, swizzled) into cA0
    #pragma unroll
    for (int q = 0; q < 4; ++q) {
        const int col = w*64 + q*16 + l15;
        #pragma unroll
        for (int m = 0; m < 2; ++m)
            #pragma unroll
            for (int j = 0; j < 4; ++j) {
                int row = m*16 + l4*4 + j;
                *(bf16*)(cA0 + swz512(row, col*2)) = (bf16)sel_f(upk[q][m][j>>1], j);
            }
    }
    __syncthreads();                               // S3

    // ---- GEMM2 per quarter; z_old from cA1 (zn*riv), z_new in place; sums narrow ----
    #pragma unroll
    for (int q = 0; q < 4; ++q) {
        const int col = w*64 + q*16 + l15;
        v4f accr[2] = {}, accs[2] = {};
        if (mode != 2) {
            __builtin_amdgcn_s_setprio(1);
            #pragma unroll
            for (int ks = 0; ks < 8; ++ks) {
                size_t bo = (size_t)col * 256 + ks*32 + l4*8;
                v8bf br_ = *(const v8bf*)(wr + bo);
                v8bf bs_ = *(const v8bf*)(wsm + bo);
                #pragma unroll
                for (int m = 0; m < 2; ++m) {
                    v8bf a = *(const v8bf*)(cA0 + swz512(m*16 + l15, ks*64 + l4*16));
                    accr[m] = MFMA(a, br_, accr[m]);
                    accs[m] = MFMA(a, bs_, accs[m]);
                }
            }
            __builtin_amdgcn_s_setprio(0);
        } else {
            __builtin_amdgcn_s_setprio(1);
            #pragma unroll
            for (int ks = 0; ks < 8; ++ks) {
                size_t bo = (size_t)col * 256 + ks*32 + l4*8;
                v8bf bs_ = *(const v8bf*)(wsm + bo);
                #pragma unroll
                for (int m = 0; m < 2; ++m) {
                    v8bf a = *(const v8bf*)(cA0 + swz512(m*16 + l15, ks*64 + l4*16));
                    accs[m] = MFMA(a, bs_, accs[m]);
                }
            }
            __builtin_amdgcn_s_setprio(0);
        }
        // load this quarter's old sums (latency covered by resident waves)
        uint4 sv;
        if (mode != 0) sv = *(const uint4*)(zb_t + q*4);
        else           sv = make_uint4(0,0,0,0);
        float bsv = bsp[col];
        if (mode != 2) {
            float brv = brp[col];
            #pragma unroll
            for (int m = 0; m < 2; ++m) {
                uint32 spair0 = (&sv.x)[m*2];
                uint32 spair1 = (&sv.x)[m*2 + 1];
                uint32 st0 = 0, st1 = 0;
                #pragma unroll
                for (int j = 0; j < 4; ++j) {
                    int row = m*16 + l4*4 + j;
                    char* zp = cA1 + swz512(row, col*2);
                    float zold = u16f(*(ushort16*)zp) * ivl[row];
                    float zf = zold + accr[m][j] + brv;
                    float sf = sel_f(j < 2 ? spair0 : spair1, j) + accs[m][j] + bsv;
                    *(ushort16*)zp = bfbits(zf);          // raw z_new in place
                    if (j < 2) st0 |= (uint32)bfbits(sf) << ((j&1)*16);
                    else       st1 |= (uint32)bfbits(sf) << ((j&1)*16);
                }
                (&sv.x)[m*2]     = st0;
                (&sv.x)[m*2 + 1] = st1;
            }
            *(uint4*)(zb_t + q*4) = sv;
        } else {
            #pragma unroll
            for (int m = 0; m < 2; ++m) {
                uint32 spair0 = (&sv.x)[m*2];
                uint32 spair1 = (&sv.x)[m*2 + 1];
                #pragma unroll
                for (int j = 0; j < 4; ++j) {
                    int row = m*16 + l4*4 + j;
                    float of = fmaxf(sel_f(j < 2 ? spair0 : spair1, j) + accs[m][j] + bsv, 0.f);
                    *(ushort16*)(cA1 + swz512(row, col*2)) = bfbits(of);   // raw o in place
                }
            }
        }
    }
    __syncthreads();                               // S4: z_new complete in cA1

    // copyout + fused rsq + normalize-at-copyout
    #pragma unroll
    for (int k = 0; k < 4; ++k) {
        int idx = tid + k * 256;
        int row = idx >> 5, d = idx & 31;
        uint4 v = *(uint4*)(cA1 + swz512(row, d*16));
        float p = sq_pair(v.x) + sq_pair(v.y) + sq_pair(v.z) + sq_pair(v.w);
        p += __shfl_xor(p,1); p += __shfl_xor(p,2); p += __shfl_xor(p,4);
        p += __shfl_xor(p,8); p += __shfl_xor(p,16);
        float iv = rsqrtf(p*(1.f/256.f) + 1e-6f);
        v.x = scale_pair(v.x, iv); v.y = scale_pair(v.y, iv);
        v.z = scale_pair(v.z, iv); v.w = scale_pair(v.w, iv);
        *((uint4*)(znout + (pr0 + row) * 256) + d) = v;
        if ((lane & 31) == 0) ivout[pr0 + row] = iv;
    }
}

// ---------------- fused head: on @ W1' -> relu -> @ W2 (8 waves, dedup'd) --------
__global__ __launch_bounds__(512, 4) void head_kernel(
    const bf16* __restrict__ on_rm,
    const bf16* __restrict__ w1b, const float* __restrict__ b1,
    const bf16* __restrict__ w2b, const float* __restrict__ b2, float* __restrict__ out) {
    __shared__ __align__(16) char smem[65536];
    char* cOn = smem;
    char* cH  = smem + 32768;
    const int tid = threadIdx.x;
    const int g0 = blockIdx.x * 64;
    const size_t pr0 = (size_t)(g0 >> 12) * TPB + PAD + (g0 & (T - 1));
    for (int i = 0; i < 4; ++i) {
        int ch = tid + i * 512;
        int r = ch >> 5, c16 = ch & 31;
        *(uint4*)(cOn + swz512(r, c16 * 16)) = *((const uint4*)(on_rm + (pr0 + r) * 256) + c16);
    }
    __syncthreads();
    const int lane = tid & 63, w = tid >> 6;
    const int l15 = lane & 15, l4 = lane >> 4;
    v4f acc2[4] = {};                       // out cols [w*16, w*16+16), all 64 rows
    for (int hc = 0; hc < 4; ++hc) {
        v4f acch[4][2] = {};
        __builtin_amdgcn_s_setprio(1);
        #pragma unroll
        for (int ks = 0; ks < 8; ++ks) {
            v8bf b0 = *(const v8bf*)(w1b + (size_t)(hc*256 + w*32 + l15) * 256 + ks*32 + l4*8);
            v8bf b1v_ = *(const v8bf*)(w1b + (size_t)(hc*256 + w*32 + 16 + l15) * 256 + ks*32 + l4*8);
            #pragma unroll
            for (int m = 0; m < 4; ++m) {
                v8bf a = *(const v8bf*)(cOn + swz512(m*16 + l15, ks*64 + l4*16));
                acch[m][0] = MFMA(a, b0, acch[m][0]);
                acch[m][1] = MFMA(a, b1v_, acch[m][1]);
            }
        }
        __builtin_amdgcn_s_setprio(0);
        __syncthreads();   // previous hc's cH reads done
        #pragma unroll
        for (int m = 0; m < 4; ++m)
            #pragma unroll
            for (int nh = 0; nh < 2; ++nh) {
                int coll = w*32 + nh*16 + l15;
                float b1v = b1[hc * 256 + coll];
                #pragma unroll
                for (int j = 0; j < 4; ++j) {
                    int row = m*16 + l4*4 + j;
                    float hv = fmaxf(acch[m][nh][j] + b1v, 0.f);
                    *(bf16*)(cH + swz512(row, coll * 2)) = (bf16)hv;
                }
            }
        __syncthreads();
        __builtin_amdgcn_s_setprio(1);
        #pragma unroll
        for (int ks = 0; ks < 8; ++ks) {
            v8bf b = *(const v8bf*)(w2b + (size_t)(w*16 + l15) * 1024 + hc * 256 + ks * 32 + l4 * 8);
            #pragma unroll
            for (int m = 0; m < 4; ++m) {
                v8bf a = *(const v8bf*)(cH + swz512(m*16 + l15, ks*64 + l4*16));
                acc2[m] = MFMA(a, b, acc2[m]);
            }
        }
        __builtin_amdgcn_s_setprio(0);
    }
    {
        int o = w*16 + l15;
        float b2v = b2[o];
        #pragma unroll
        for (int m = 0; m < 4; ++m)
            #pragma unroll
            for (int j = 0; j < 4; ++j) {
                int row = m*16 + l4*4 + j;
                out[(size_t)(g0 + row) * 128 + o] = acc2[m][j] + b2v;
            }
    }
}

extern "C" void kernel_launch(void* const* d_in, const int* in_sizes, int n_in,
                              void* d_out, int out_size, void* d_ws, size_t ws_size,
                              hipStream_t stream) {
    const float* x      = (const float*)d_in[0];
    const float* W_in   = (const float*)d_in[1];
    const float* b_in   = (const float*)d_in[2];
    const float* W_f    = (const float*)d_in[3];
    const float* b_f    = (const float*)d_in[4];
    const float* W_g    = (const float*)d_in[5];
    const float* b_g    = (const float*)d_in[6];
    const float* W_r    = (const float*)d_in[7];
    const float* b_r    = (const float*)d_in[8];
    const float* W_s    = (const float*)d_in[9];
    const float* b_s    = (const float*)d_in[10];
    const float* norm_w = (const float*)d_in[11];
    const float* hnw    = (const float*)d_in[12];
    const float* W1     = (const float*)d_in[13];
    const float* b1     = (const float*)d_in[14];
    const float* W2     = (const float*)d_in[15];
    const float* b2     = (const float*)d_in[16];

    char* p = (char*)d_ws;
    bf16*  zn_a = (bf16*)p;            p += (size_t)16 * TPB * 256 * 2;
    bf16*  zn_b = (bf16*)p;            p += (size_t)16 * TPB * 256 * 2;
    float* iv_a = (float*)p;           p += (size_t)16 * TPB * 4;
    float* iv_b = (float*)p;           p += (size_t)16 * TPB * 4;
    uint32* sumb = (uint32*)p;         p += (size_t)BT * 128 * 4;   // 512B per token
    bf16* wf0   = (bf16*)p;            p += (size_t)NL * 65536 * 2;
    bf16* wf1   = (bf16*)p;            p += (size_t)NL * 65536 * 2;
    bf16* wg0   = (bf16*)p;            p += (size_t)NL * 65536 * 2;
    bf16* wg1   = (bf16*)p;            p += (size_t)NL * 65536 * 2;
    bf16* wr    = (bf16*)p;            p += (size_t)NL * 65536 * 2;
    bf16* ws    = (bf16*)p;            p += (size_t)NL * 65536 * 2;
    bf16* winb  = (bf16*)p;            p += 65536 * 2;
    bf16* w1b   = (bf16*)p;            p += 262144 * 2;
    bf16* w2b   = (bf16*)p;            p += 131072 * 2;

    zero_pads<<<2064, 256, 0, stream>>>(zn_a, zn_b, iv_a, iv_b);
    prep_w2<<<NL * 256, 256, 0, stream>>>(W_f, W_g, norm_w, wf0, wf1, wg0, wg1);
    prep_w1<<<NL * 256, 256, 0, stream>>>(W_r, W_s, wr, ws);
    prep_misc<<<1792, 256, 0, stream>>>(W_in, W1, W2, hnw, winb, w1b, w2b);
    in_conv_kernel<<<BT / 64, 512, 0, stream>>>(x, winb, b_in, zn_a, iv_a);

    static const int dil[NL] = {1,2,4,8,16,32,64,128,256,512,
                                1,2,4,8,16,32,64,128,256,512};
    for (int i = 0; i < NL; ++i) {
        const bf16* zi  = (i & 1) ? zn_b : zn_a;
        bf16* zo_       = (i & 1) ? zn_a : zn_b;
        const float* ii = (i & 1) ? iv_b : iv_a;
        float* io       = (i & 1) ? iv_a : iv_b;
        int mode = (i == 0) ? 0 : ((i == NL - 1) ? 2 : 1);
        layer_kernel<<<BT / 32, 256, 0, stream>>>(zi, ii, zo_, io, sumb,
            wf0 + (size_t)i * 65536, wf1 + (size_t)i * 65536,
            wg0 + (size_t)i * 65536, wg1 + (size_t)i * 65536,
            wr + (size_t)i * 65536, ws + (size_t)i * 65536,
            b_f + i * 256, b_g + i * 256, b_r + i * 256, b_s + i * 256,
            dil[i], mode);
    }
    // NL=20 even: last layer wrote zn_a (normalized o for head)
    head_kernel<<<BT / 64, 512, 0, stream>>>(zn_a, w1b, b1, w2b, b2, (float*)d_out);
}

// Round 18
// 2283.270 us; speedup vs baseline: 1.6738x; 1.6738x over previous
//
#include <hip/hip_runtime.h>
#include <hip/hip_bf16.h>

#define T 4096
#define BT (16*4096)
#define NL 20
#define TPB 4608   // 512 pad + 4096 tokens per batch
#define PAD 512

typedef __bf16 bf16;
typedef __bf16 v8bf __attribute__((ext_vector_type(8)));
typedef float v4f __attribute__((ext_vector_type(4)));
typedef unsigned int uint32;
typedef unsigned short ushort16;

#define MFMA(a,b,c) __builtin_amdgcn_mfma_f32_16x16x32_bf16((a),(b),(c),0,0,0)

__device__ __forceinline__ int swz512(int row, int bc)  { return row*512  + (bc ^ ((row&7)<<4)); }

__device__ __forceinline__ void gload16(const void* g, void* l) {
    __builtin_amdgcn_global_load_lds(
        (const __attribute__((address_space(1))) void*)g,
        (__attribute__((address_space(3))) void*)l, 16, 0, 0);
}

__device__ __forceinline__ ushort16 bfbits(float v) {
    bf16 h = (bf16)v; return *(ushort16*)&h;
}
__device__ __forceinline__ float u16f(uint32 lo16) { uint32 t = lo16 << 16; return *(float*)&t; }
__device__ __forceinline__ float sel_f(uint32 pair, int j) {  // j&1: 0=lo,1=hi
    uint32 t = (j & 1) ? (pair & 0xffff0000u) : (pair << 16);
    return *(float*)&t;
}
__device__ __forceinline__ uint32 scale_pair(uint32 v, float s) {
    uint32 lo = v << 16, hi = v & 0xffff0000u;
    float flo = *(float*)&lo * s, fhi = *(float*)&hi * s;
    return (uint32)bfbits(flo) | ((uint32)bfbits(fhi) << 16);
}
__device__ __forceinline__ float sq_pair(uint32 v) {
    uint32 lo = v << 16, hi = v & 0xffff0000u;
    float flo = *(float*)&lo, fhi = *(float*)&hi;
    return flo*flo + fhi*fhi;
}
// u = tanh(f) * sigmoid(g) with a single division:
// tanh(f) = (1-e^-2f)/(1+e^-2f), sigmoid(g) = 1/(1+e^-g)
__device__ __forceinline__ float gated_u(float fv, float gv) {
    fv = fminf(fmaxf(fv, -20.f), 20.f);
    float e2 = __expf(-2.f * fv);
    float eg = __expf(-gv);
    return (1.f - e2) / ((1.f + e2) * (1.f + eg));
}

// ---------------- zero pad stripes of zn ping-pong and iv ping-pong buffers ----------------
__global__ void zero_pads(bf16* __restrict__ za, bf16* __restrict__ zb,
                          float* __restrict__ iva, float* __restrict__ ivb) {
    int idx = blockIdx.x * 256 + threadIdx.x;      // 524288 + 4096 uint4
    if (idx < 524288) {
        int buf = idx >> 18;
        int r = idx & 262143;
        int b = r >> 14, off = r & 16383;          // pad = 512 rows * 32 uint4
        bf16* base = buf ? zb : za;
        ((uint4*)(base + (size_t)b * TPB * 256))[off] = make_uint4(0, 0, 0, 0);
    } else {
        int j = idx - 524288;                      // 2 bufs * 16 batches * 128 uint4
        int buf = j >> 11;
        int r = j & 2047;
        int b = r >> 7, off = r & 127;
        float* base = buf ? ivb : iva;
        ((uint4*)(base + (size_t)b * TPB))[off] = make_uint4(0, 0, 0, 0);
    }
}

// ---------------- prep kernels: cast/reorder weights to bf16 (norm_w folded into K) ----------
__global__ void prep_w2(const float* __restrict__ Wf, const float* __restrict__ Wg,
                        const float* __restrict__ norm_w,
                        bf16* __restrict__ wf0, bf16* __restrict__ wf1,
                        bf16* __restrict__ wg0, bf16* __restrict__ wg1) {
    int idx = blockIdx.x * 256 + threadIdx.x;       // NL*256*256, (layer, n, k)
    float nwv = norm_w[(idx >> 16) * 256 + (idx & 255)];
    const float* pf = Wf + (size_t)idx * 2;
    wf0[idx] = (bf16)(pf[0] * nwv); wf1[idx] = (bf16)(pf[1] * nwv);
    const float* pg = Wg + (size_t)idx * 2;
    wg0[idx] = (bf16)(pg[0] * nwv); wg1[idx] = (bf16)(pg[1] * nwv);
}

__global__ void prep_w1(const float* __restrict__ Wr, const float* __restrict__ Ws,
                        bf16* __restrict__ wr, bf16* __restrict__ ws) {
    int idx = blockIdx.x * 256 + threadIdx.x;       // NL*256*256 (A=U, no norm fold)
    wr[idx] = (bf16)Wr[idx]; ws[idx] = (bf16)Ws[idx];
}

__global__ void prep_misc(const float* __restrict__ W_in, const float* __restrict__ W1,
                          const float* __restrict__ W2, const float* __restrict__ hnw,
                          bf16* __restrict__ winb, bf16* __restrict__ w1b, bf16* __restrict__ w2b) {
    int idx = blockIdx.x * 256 + threadIdx.x;       // 458752 total
    if (idx < 65536) {
        int c = idx >> 8, jj = idx & 255, k = jj >> 3, ci = jj & 7;
        winb[idx] = (bf16)W_in[c * 256 + ci * 32 + k];   // winb[c][k*8+ci]
    } else if (idx < 327680) {
        int j = idx - 65536;                             // (h, k): fold head norm weight
        w1b[j] = (bf16)(W1[j] * hnw[j & 255]);
    } else {
        int j = idx - 327680; w2b[j] = (bf16)W2[j];
    }
}

// ---------------- fused input conv: x windows -> zn (normalized bf16) + iv ----------------
__global__ __launch_bounds__(512, 4) void in_conv_kernel(
    const float* __restrict__ x, const bf16* __restrict__ winb,
    const float* __restrict__ b_in,
    bf16* __restrict__ znout, float* __restrict__ ivout) {
    __shared__ __align__(16) char smem[65536];
    char* cW  = smem + 32768;                 // window tile
    char* cZn = smem;                         // z staging
    const int tid = threadIdx.x;
    const int g0 = blockIdx.x * 64;
    const int tl0 = g0 & (T - 1);
    const size_t pr0 = (size_t)(g0 >> 12) * TPB + PAD + tl0;
    for (int i = 0; i < 4; ++i) {
        int ch = tid + i * 512;
        int r = ch >> 5, c16 = ch & 31;
        int tok = tl0 + r - 31 + c16;
        bf16 t8[8] = {};
        if (tok >= 0) {
            const float* xr = x + (size_t)(g0 + r - 31 + c16) * 8;
            float4 xa = ((const float4*)xr)[0];
            float4 xb4 = ((const float4*)xr)[1];
            t8[0]=(bf16)xa.x; t8[1]=(bf16)xa.y; t8[2]=(bf16)xa.z; t8[3]=(bf16)xa.w;
            t8[4]=(bf16)xb4.x; t8[5]=(bf16)xb4.y; t8[6]=(bf16)xb4.z; t8[7]=(bf16)xb4.w;
        }
        *(uint4*)(cW + swz512(r, c16 * 16)) = *(uint4*)t8;
    }
    __syncthreads();
    const int lane = tid & 63, w = tid >> 6;
    const int l15 = lane & 15, l4 = lane >> 4;
    const int cbase = w * 32 + l15;

    uint32 zpk[2][4][2] = {};
    #pragma unroll
    for (int half = 0; half < 2; ++half) {
        v4f acc[4] = {};
        __builtin_amdgcn_s_setprio(1);
        #pragma unroll
        for (int ks = 0; ks < 8; ++ks) {
            v8bf b = *(const v8bf*)(winb + (size_t)(cbase + half*16)*256 + ks*32 + l4*8);
            #pragma unroll
            for (int m = 0; m < 4; ++m) {
                v8bf a = *(const v8bf*)(cW + swz512(m*16 + l15, ks*64 + l4*16));
                acc[m] = MFMA(a, b, acc[m]);
            }
        }
        __builtin_amdgcn_s_setprio(0);
        float bv = b_in[cbase + half*16];
        #pragma unroll
        for (int m = 0; m < 4; ++m)
            #pragma unroll
            for (int j = 0; j < 4; ++j) {
                float zf = acc[m][j] + bv;
                zpk[half][m][j>>1] |= (uint32)bfbits(zf) << ((j&1)*16);
            }
    }
    __syncthreads();                                  // window reads done
    #pragma unroll
    for (int m = 0; m < 4; ++m)
        #pragma unroll
        for (int j = 0; j < 4; ++j) {
            int row = m*16 + l4*4 + j;
            #pragma unroll
            for (int half = 0; half < 2; ++half) {
                int col = cbase + half*16;
                *(bf16*)(cZn + swz512(row, col*2)) = (bf16)sel_f(zpk[half][m][j>>1], j);
            }
        }
    __syncthreads();                                  // z tile complete
    // copyout + fused rsq + normalize-at-copyout (32 lanes per row hold the full row)
    #pragma unroll
    for (int k = 0; k < 4; ++k) {
        int idx = tid + k * 512;
        int row = idx >> 5, d = idx & 31;
        uint4 v = *(uint4*)(cZn + swz512(row, d*16));
        float p = sq_pair(v.x) + sq_pair(v.y) + sq_pair(v.z) + sq_pair(v.w);
        p += __shfl_xor(p,1); p += __shfl_xor(p,2); p += __shfl_xor(p,4);
        p += __shfl_xor(p,8); p += __shfl_xor(p,16);
        float iv = rsqrtf(p*(1.f/256.f) + 1e-6f);
        v.x = scale_pair(v.x, iv); v.y = scale_pair(v.y, iv);
        v.z = scale_pair(v.z, iv); v.w = scale_pair(v.w, iv);
        *((uint4*)(znout + (pr0 + row) * 256) + d) = v;
        if ((lane & 31) == 0) ivout[pr0 + row] = iv;
    }
}

// ---------------- fused gated-residual layer ----------------
// zn exchanged normalized (bf16) + per-token iv (for residual reconstruction);
// z_new normalized at copyout. mode: 0=first,1=mid,2=last
__global__ __launch_bounds__(512, 4) void layer_kernel(
    const bf16* __restrict__ znin, const float* __restrict__ ivin,
    bf16* __restrict__ znout, float* __restrict__ ivout, uint32* __restrict__ sumb,
    const bf16* __restrict__ wf0, const bf16* __restrict__ wf1,
    const bf16* __restrict__ wg0, const bf16* __restrict__ wg1,
    const bf16* __restrict__ wr, const bf16* __restrict__ wsm,
    const float* __restrict__ bfp, const float* __restrict__ bgp,
    const float* __restrict__ brp, const float* __restrict__ bsp,
    int dil, int mode) {
    __shared__ __align__(16) char smem[65792];
    char* cA0 = smem;                     // zn[t-d] -> U tile
    char* cA1 = smem + 32768;             // zn[t] -> z_new (in place)
    float* ivl = (float*)(smem + 65536);  // [0..63] = 1/iv[t] (riv for residual)
    const int tid = threadIdx.x;
    const int lane = tid & 63, w = tid >> 6;
    const int g0 = blockIdx.x * 64;
    const size_t pr0 = (size_t)(g0 >> 12) * TPB + PAD + (g0 & (T - 1));

    const int rl = w * 8 + (lane >> 5);

    // async stage zn[t]->cA1, zn[t-dil]->cA0 with pre-swizzled global source
    {
        int d = lane & 31;
        #pragma unroll
        for (int j = 0; j < 4; ++j) {
            int r = rl + j * 2;
            int s = d ^ (r & 7);
            gload16(znin + (pr0 + r) * 256 + s * 8,       cA1 + (w*8 + j*2) * 512);
            gload16(znin + (pr0 + r - dil) * 256 + s * 8, cA0 + (w*8 + j*2) * 512);
        }
    }
    if (tid < 64) ivl[tid] = 1.f / ivin[pr0 + tid];   // riv for z_old reconstruction

    const int l15 = lane & 15, l4 = lane >> 4;
    const int cbase = w * 32 + l15;
    uint32* zb_t = sumb + ((size_t)blockIdx.x * 512 + tid) * 16;

    __syncthreads();                               // S1: staging + ivl visible

    // ---- GEMM1: fused taps, 2 col-halves (tiles arrive pre-normalized) ----
    uint32 upk[2][4][2] = {};                      // [half][m][jpair] packed bf16 u
    #pragma unroll
    for (int half = 0; half < 2; ++half) {
        v4f accf[4] = {}, accg[4] = {};
        __builtin_amdgcn_s_setprio(1);
        #pragma unroll
        for (int ks = 0; ks < 8; ++ks) {
            size_t bo = (size_t)(cbase + half*16) * 256 + ks*32 + l4*8;
            v8bf bf0 = *(const v8bf*)(wf0 + bo);
            v8bf bf1 = *(const v8bf*)(wf1 + bo);
            v8bf bg0 = *(const v8bf*)(wg0 + bo);
            v8bf bg1 = *(const v8bf*)(wg1 + bo);
            #pragma unroll
            for (int m = 0; m < 4; ++m) {
                int off = swz512(m*16 + l15, ks*64 + l4*16);
                v8bf a0 = *(const v8bf*)(cA0 + off);
                v8bf a1 = *(const v8bf*)(cA1 + off);
                accf[m] = MFMA(a0, bf0, accf[m]);
                accf[m] = MFMA(a1, bf1, accf[m]);
                accg[m] = MFMA(a0, bg0, accg[m]);
                accg[m] = MFMA(a1, bg1, accg[m]);
            }
        }
        __builtin_amdgcn_s_setprio(0);
        float bfv = bfp[cbase + half*16];
        float bgv = bgp[cbase + half*16];
        #pragma unroll
        for (int m = 0; m < 4; ++m)
            #pragma unroll
            for (int j = 0; j < 4; ++j) {
                float u = gated_u(accf[m][j] + bfv, accg[m][j] + bgv);
                upk[half][m][j>>1] |= (uint32)bfbits(u) << ((j&1)*16);
            }
    }
    __syncthreads();                               // S2: all GEMM1 tile reads done (cA0 free)

    // write U tile (bf16, swizzled) into cA0
    #pragma unroll
    for (int half = 0; half < 2; ++half)
        #pragma unroll
        for (int m = 0; m < 4; ++m) {
            int col = cbase + half*16;
            #pragma unroll
            for (int j = 0; j < 4; ++j) {
                int row = m*16 + l4*4 + j;
                *(bf16*)(cA0 + swz512(row, col*2)) = (bf16)sel_f(upk[half][m][j>>1], j);
            }
        }
    __syncthreads();                               // S3

    // ---- GEMM2 per half; z_old from cA1 (zn*riv), z_new in place; sums loaded in epilogue ----
    #pragma unroll
    for (int half = 0; half < 2; ++half) {
        v4f accr[4] = {}, accs[4] = {};
        if (mode != 2) {
            __builtin_amdgcn_s_setprio(1);
            #pragma unroll
            for (int ks = 0; ks < 8; ++ks) {
                size_t bo = (size_t)(cbase + half*16) * 256 + ks*32 + l4*8;
                v8bf br_ = *(const v8bf*)(wr + bo);
                v8bf bs_ = *(const v8bf*)(wsm + bo);
                #pragma unroll
                for (int m = 0; m < 4; ++m) {
                    v8bf a = *(const v8bf*)(cA0 + swz512(m*16 + l15, ks*64 + l4*16));
                    accr[m] = MFMA(a, br_, accr[m]);
                    accs[m] = MFMA(a, bs_, accs[m]);
                }
            }
            __builtin_amdgcn_s_setprio(0);
        } else {
            __builtin_amdgcn_s_setprio(1);
            #pragma unroll
            for (int ks = 0; ks < 8; ++ks) {
                size_t bo = (size_t)(cbase + half*16) * 256 + ks*32 + l4*8;
                v8bf bs_ = *(const v8bf*)(wsm + bo);
                #pragma unroll
                for (int m = 0; m < 4; ++m) {
                    v8bf a = *(const v8bf*)(cA0 + swz512(m*16 + l15, ks*64 + l4*16));
                    accs[m] = MFMA(a, bs_, accs[m]);
                }
            }
            __builtin_amdgcn_s_setprio(0);
        }
        // load this half's old sums now (latency covered by resident waves)
        uint4 s0_, s1_;
        if (mode != 0) {
            s0_ = *(const uint4*)(zb_t + half*8);
            s1_ = *(const uint4*)(zb_t + half*8 + 4);
        } else {
            s0_ = make_uint4(0,0,0,0); s1_ = make_uint4(0,0,0,0);
        }
        int col = cbase + half*16;
        float bsv = bsp[col];
        if (mode != 2) {
            float brv = brp[col];
            #pragma unroll
            for (int m = 0; m < 4; ++m) {
                uint4& sv = (m < 2) ? s0_ : s1_;
                uint32 spair0 = (&sv.x)[(m&1)*2];
                uint32 spair1 = (&sv.x)[(m&1)*2 + 1];
                uint32 st0 = 0, st1 = 0;
                #pragma unroll
                for (int j = 0; j < 4; ++j) {
                    int row = m*16 + l4*4 + j;
                    char* zp = cA1 + swz512(row, col*2);
                    float zold = u16f(*(ushort16*)zp) * ivl[row];
                    float zf = zold + accr[m][j] + brv;
                    float sf = sel_f(j < 2 ? spair0 : spair1, j) + accs[m][j] + bsv;
                    *(ushort16*)zp = bfbits(zf);          // raw z_new in place
                    if (j < 2) st0 |= (uint32)bfbits(sf) << ((j&1)*16);
                    else       st1 |= (uint32)bfbits(sf) << ((j&1)*16);
                }
                (&sv.x)[(m&1)*2]     = st0;
                (&sv.x)[(m&1)*2 + 1] = st1;
            }
            *(uint4*)(zb_t + half*8)     = s0_;
            *(uint4*)(zb_t + half*8 + 4) = s1_;
        } else {
            #pragma unroll
            for (int m = 0; m < 4; ++m) {
                uint4& sv = (m < 2) ? s0_ : s1_;
                uint32 spair0 = (&sv.x)[(m&1)*2];
                uint32 spair1 = (&sv.x)[(m&1)*2 + 1];
                #pragma unroll
                for (int j = 0; j < 4; ++j) {
                    int row = m*16 + l4*4 + j;
                    float of = fmaxf(sel_f(j < 2 ? spair0 : spair1, j) + accs[m][j] + bsv, 0.f);
                    *(ushort16*)(cA1 + swz512(row, col*2)) = bfbits(of);   // raw o in place
                }
            }
        }
    }
    __syncthreads();                               // S4: z_new complete in cA1

    // copyout + fused rsq + normalize-at-copyout
    #pragma unroll
    for (int k = 0; k < 4; ++k) {
        int idx = tid + k * 512;
        int row = idx >> 5, d = idx & 31;
        uint4 v = *(uint4*)(cA1 + swz512(row, d*16));
        float p = sq_pair(v.x) + sq_pair(v.y) + sq_pair(v.z) + sq_pair(v.w);
        p += __shfl_xor(p,1); p += __shfl_xor(p,2); p += __shfl_xor(p,4);
        p += __shfl_xor(p,8); p += __shfl_xor(p,16);
        float iv = rsqrtf(p*(1.f/256.f) + 1e-6f);
        v.x = scale_pair(v.x, iv); v.y = scale_pair(v.y, iv);
        v.z = scale_pair(v.z, iv); v.w = scale_pair(v.w, iv);
        *((uint4*)(znout + (pr0 + row) * 256) + d) = v;
        if ((lane & 31) == 0) ivout[pr0 + row] = iv;
    }
}

// ---------------- fused head: on @ W1' -> relu -> @ W2 (8 waves, dedup'd) --------
__global__ __launch_bounds__(512, 4) void head_kernel(
    const bf16* __restrict__ on_rm,
    const bf16* __restrict__ w1b, const float* __restrict__ b1,
    const bf16* __restrict__ w2b, const float* __restrict__ b2, float* __restrict__ out) {
    __shared__ __align__(16) char smem[65536];
    char* cOn = smem;
    char* cH  = smem + 32768;
    const int tid = threadIdx.x;
    const int g0 = blockIdx.x * 64;
    const size_t pr0 = (size_t)(g0 >> 12) * TPB + PAD + (g0 & (T - 1));
    for (int i = 0; i < 4; ++i) {
        int ch = tid + i * 512;
        int r = ch >> 5, c16 = ch & 31;
        *(uint4*)(cOn + swz512(r, c16 * 16)) = *((const uint4*)(on_rm + (pr0 + r) * 256) + c16);
    }
    __syncthreads();
    const int lane = tid & 63, w = tid >> 6;
    const int l15 = lane & 15, l4 = lane >> 4;
    v4f acc2[4] = {};                       // out cols [w*16, w*16+16), all 64 rows
    for (int hc = 0; hc < 4; ++hc) {
        v4f acch[4][2] = {};
        __builtin_amdgcn_s_setprio(1);
        #pragma unroll
        for (int ks = 0; ks < 8; ++ks) {
            v8bf b0 = *(const v8bf*)(w1b + (size_t)(hc*256 + w*32 + l15) * 256 + ks*32 + l4*8);
            v8bf b1v_ = *(const v8bf*)(w1b + (size_t)(hc*256 + w*32 + 16 + l15) * 256 + ks*32 + l4*8);
            #pragma unroll
            for (int m = 0; m < 4; ++m) {
                v8bf a = *(const v8bf*)(cOn + swz512(m*16 + l15, ks*64 + l4*16));
                acch[m][0] = MFMA(a, b0, acch[m][0]);
                acch[m][1] = MFMA(a, b1v_, acch[m][1]);
            }
        }
        __builtin_amdgcn_s_setprio(0);
        __syncthreads();   // previous hc's cH reads done
        #pragma unroll
        for (int m = 0; m < 4; ++m)
            #pragma unroll
            for (int nh = 0; nh < 2; ++nh) {
                int coll = w*32 + nh*16 + l15;
                float b1v = b1[hc * 256 + coll];
                #pragma unroll
                for (int j = 0; j < 4; ++j) {
                    int row = m*16 + l4*4 + j;
                    float hv = fmaxf(acch[m][nh][j] + b1v, 0.f);
                    *(bf16*)(cH + swz512(row, coll * 2)) = (bf16)hv;
                }
            }
        __syncthreads();
        __builtin_amdgcn_s_setprio(1);
        #pragma unroll
        for (int ks = 0; ks < 8; ++ks) {
            v8bf b = *(const v8bf*)(w2b + (size_t)(w*16 + l15) * 1024 + hc * 256 + ks * 32 + l4 * 8);
            #pragma unroll
            for (int m = 0; m < 4; ++m) {
                v8bf a = *(const v8bf*)(cH + swz512(m*16 + l15, ks*64 + l4*16));
                acc2[m] = MFMA(a, b, acc2[m]);
            }
        }
        __builtin_amdgcn_s_setprio(0);
    }
    {
        int o = w*16 + l15;
        float b2v = b2[o];
        #pragma unroll
        for (int m = 0; m < 4; ++m)
            #pragma unroll
            for (int j = 0; j < 4; ++j) {
                int row = m*16 + l4*4 + j;
                out[(size_t)(g0 + row) * 128 + o] = acc2[m][j] + b2v;
            }
    }
}

extern "C" void kernel_launch(void* const* d_in, const int* in_sizes, int n_in,
                              void* d_out, int out_size, void* d_ws, size_t ws_size,
                              hipStream_t stream) {
    const float* x      = (const float*)d_in[0];
    const float* W_in   = (const float*)d_in[1];
    const float* b_in   = (const float*)d_in[2];
    const float* W_f    = (const float*)d_in[3];
    const float* b_f    = (const float*)d_in[4];
    const float* W_g    = (const float*)d_in[5];
    const float* b_g    = (const float*)d_in[6];
    const float* W_r    = (const float*)d_in[7];
    const float* b_r    = (const float*)d_in[8];
    const float* W_s    = (const float*)d_in[9];
    const float* b_s    = (const float*)d_in[10];
    const float* norm_w = (const float*)d_in[11];
    const float* hnw    = (const float*)d_in[12];
    const float* W1     = (const float*)d_in[13];
    const float* b1     = (const float*)d_in[14];
    const float* W2     = (const float*)d_in[15];
    const float* b2     = (const float*)d_in[16];

    char* p = (char*)d_ws;
    bf16*  zn_a = (bf16*)p;            p += (size_t)16 * TPB * 256 * 2;
    bf16*  zn_b = (bf16*)p;            p += (size_t)16 * TPB * 256 * 2;
    float* iv_a = (float*)p;           p += (size_t)16 * TPB * 4;
    float* iv_b = (float*)p;           p += (size_t)16 * TPB * 4;
    uint32* sumb = (uint32*)p;         p += (size_t)BT * 128 * 4;   // 512B per token
    bf16* wf0   = (bf16*)p;            p += (size_t)NL * 65536 * 2;
    bf16* wf1   = (bf16*)p;            p += (size_t)NL * 65536 * 2;
    bf16* wg0   = (bf16*)p;            p += (size_t)NL * 65536 * 2;
    bf16* wg1   = (bf16*)p;            p += (size_t)NL * 65536 * 2;
    bf16* wr    = (bf16*)p;            p += (size_t)NL * 65536 * 2;
    bf16* ws    = (bf16*)p;            p += (size_t)NL * 65536 * 2;
    bf16* winb  = (bf16*)p;            p += 65536 * 2;
    bf16* w1b   = (bf16*)p;            p += 262144 * 2;
    bf16* w2b   = (bf16*)p;            p += 131072 * 2;

    zero_pads<<<2064, 256, 0, stream>>>(zn_a, zn_b, iv_a, iv_b);
    prep_w2<<<NL * 256, 256, 0, stream>>>(W_f, W_g, norm_w, wf0, wf1, wg0, wg1);
    prep_w1<<<NL * 256, 256, 0, stream>>>(W_r, W_s, wr, ws);
    prep_misc<<<1792, 256, 0, stream>>>(W_in, W1, W2, hnw, winb, w1b, w2b);
    in_conv_kernel<<<BT / 64, 512, 0, stream>>>(x, winb, b_in, zn_a, iv_a);

    static const int dil[NL] = {1,2,4,8,16,32,64,128,256,512,
                                1,2,4,8,16,32,64,128,256,512};
    for (int i = 0; i < NL; ++i) {
        const bf16* zi  = (i & 1) ? zn_b : zn_a;
        bf16* zo_       = (i & 1) ? zn_a : zn_b;
        const float* ii = (i & 1) ? iv_b : iv_a;
        float* io       = (i & 1) ? iv_a : iv_b;
        int mode = (i == 0) ? 0 : ((i == NL - 1) ? 2 : 1);
        layer_kernel<<<BT / 64, 512, 0, stream>>>(zi, ii, zo_, io, sumb,
            wf0 + (size_t)i * 65536, wf1 + (size_t)i * 65536,
            wg0 + (size_t)i * 65536, wg1 + (size_t)i * 65536,
            wr + (size_t)i * 65536, ws + (size_t)i * 65536,
            b_f + i * 256, b_g + i * 256, b_r + i * 256, b_s + i * 256,
            dil[i], mode);
    }
    // NL=20 even: last layer wrote zn_a (normalized o for head)
    head_kernel<<<BT / 64, 512, 0, stream>>>(zn_a, w1b, b1, w2b, b2, (float*)d_out);
}